// Round 7
// baseline (196.903 us; speedup 1.0000x reference)
//
#include <hip/hip_runtime.h>
#include <math.h>

typedef __attribute__((ext_vector_type(8))) short short8;
typedef __attribute__((ext_vector_type(4))) float f32x4;
typedef unsigned short u16;

#define NNPTS 131072          // B*N*K
#define NQ    8192            // B*N

__device__ __forceinline__ u16 f2bf(float f) {
  unsigned u = __float_as_uint(f);
  u = u + 0x7fffu + ((u >> 16) & 1u);
  return (u16)(u >> 16);
}
__device__ __forceinline__ float bf2f(u16 h) {
  return __uint_as_float(((unsigned)h) << 16);
}

// ---------------- transpose features [B][C][N] -> featB bf16 [B][N][C] ----------------
__global__ __launch_bounds__(256) void transpose_feat(const float* __restrict__ f,
                                                      u16* __restrict__ featB)
{
  __shared__ float T[64][65];
  int tx = threadIdx.x & 63, tg = threadIdx.x >> 6;
  int n0 = blockIdx.x * 64, c0 = blockIdx.y * 64, b = blockIdx.z;
  const float* src = f + ((size_t)b * 128 + c0) * 4096 + n0;
  #pragma unroll
  for (int it = 0; it < 16; ++it) {
    int cl = tg + it * 4;
    T[cl][tx] = src[(size_t)cl * 4096 + tx];
  }
  __syncthreads();
  u16* dst = featB + ((size_t)b * 4096 + n0) * 128 + c0;
  #pragma unroll
  for (int it = 0; it < 16; ++it) {
    int nl = tg + it * 4;
    dst[(size_t)nl * 128 + tx] = f2bf(T[tx][nl]);
  }
}

// ---------------- weight prep: bf16 casts + fused products ----------------
__global__ __launch_bounds__(128) void prep_weights(
    const float* __restrict__ wphi, const float* __restrict__ wpsi,
    const float* __restrict__ walpha,
    const float* __restrict__ wg1, const float* __restrict__ wg2,
    const float* __restrict__ bg1, const float* __restrict__ bg2,
    const float* __restrict__ wt1, const float* __restrict__ bt1,
    const float* __restrict__ wt2, const float* __restrict__ bt2,
    u16* __restrict__ WphiB, u16* __restrict__ WpsiB, u16* __restrict__ WalphaB,
    u16* __restrict__ WfusB, float* __restrict__ c0,
    float* __restrict__ Wc, float* __restrict__ bc)
{
  int cc = blockIdx.x, i = threadIdx.x;
  WphiB[cc*128+i]   = f2bf(wphi[cc*128+i]);
  WpsiB[cc*128+i]   = f2bf(wpsi[cc*128+i]);
  WalphaB[cc*128+i] = f2bf(walpha[cc*128+i]);
  float s = 0.f;
  for (int t = 0; t < 128; ++t) s = fmaf(wg2[cc*128+t], wg1[t*128+i], s);
  WfusB[cc*128+i] = f2bf(s);
  if (i == 0) {
    float s0 = bg2[cc];
    for (int t = 0; t < 128; ++t) s0 = fmaf(wg2[cc*128+t], bg1[t], s0);
    c0[cc] = s0;
    for (int j = 0; j < 3; ++j) {
      float a = 0.f;
      for (int t = 0; t < 128; ++t) a = fmaf(wt2[cc*128+t], wt1[t*3+j], a);
      Wc[cc*3+j] = a;
    }
    float bb = bt2[cc];
    for (int t = 0; t < 128; ++t) bb = fmaf(wt2[cc*128+t], bt1[t], bb);
    bc[cc] = bb;
  }
}

// ---------------- KNN: wave per query, register top-4 lists, no barriers ----------------
__global__ __launch_bounds__(256) void knn_kernel(const float* __restrict__ xyz,
                                                  int* __restrict__ idxOut)
{
  int tid = threadIdx.x, lane = tid & 63, wid = tid >> 6;
  int q = blockIdx.x * 4 + wid;
  int b = q >> 12, n = q & 4095;
  const float* X = xyz + (size_t)b * 12288;
  float qx = X[n], qy = X[4096+n], qz = X[8192+n];
  float xxq = __fadd_rn(__fadd_rn(__fmul_rn(qx,qx), __fmul_rn(qy,qy)), __fmul_rn(qz,qz));

  float v0=-INFINITY, v1=-INFINITY, v2=-INFINITY, v3=-INFINITY;
  int   i0=0x7fffffff, i1=0x7fffffff, i2=0x7fffffff, i3=0x7fffffff;
  unsigned long long alive = ~0ull;

  #pragma unroll 4
  for (int j = 0; j < 64; ++j) {
    int m = j*64 + lane;
    float mx = X[m], my = X[4096+m], mz = X[8192+m];
    float xxm = __fadd_rn(__fadd_rn(__fmul_rn(mx,mx), __fmul_rn(my,my)), __fmul_rn(mz,mz));
    float dot = __fadd_rn(__fadd_rn(__fmul_rn(qx,mx), __fmul_rn(qy,my)), __fmul_rn(qz,mz));
    float inner = __fmul_rn(-2.0f, dot);
    float dv = __fsub_rn(__fsub_rn(-xxm, inner), xxq);   // exact ref order
    bool c0_ = dv > v0, c1_ = dv > v1, c2_ = dv > v2, c3_ = dv > v3;
    float nv1 = c0_ ? v0 : (c1_ ? dv : v1); int ni1 = c0_ ? i0 : (c1_ ? m : i1);
    float nv2 = c1_ ? v1 : (c2_ ? dv : v2); int ni2 = c1_ ? i1 : (c2_ ? m : i2);
    float nv3 = c2_ ? v2 : (c3_ ? dv : v3); int ni3 = c2_ ? i2 : (c3_ ? m : i3);
    v0 = c0_ ? dv : v0; i0 = c0_ ? m : i0;
    v1 = nv1; i1 = ni1; v2 = nv2; i2 = ni2; v3 = nv3; i3 = ni3;
  }

  int cnt = 4;
  for (int r = 0; r < 16; ++r) {
    float gv = v0; int gi = i0;
    #pragma unroll
    for (int d = 1; d < 64; d <<= 1) {
      float ov = __shfl_xor(gv, d); int oi = __shfl_xor(gi, d);
      if (ov > gv || (ov == gv && oi < gi)) { gv = ov; gi = oi; }
    }
    if (lane == 0) idxOut[(size_t)q*16 + r] = gi;
    if (lane == (gi & 63)) {
      alive &= ~(1ull << (gi >> 6));
      v0=v1; i0=i1; v1=v2; i1=i2; v2=v3; i2=i3; v3=-INFINITY; i3=0x7fffffff;
      if (--cnt == 0 && r < 15) {
        v0=v1=v2=v3=-INFINITY; i0=i1=i2=i3=0x7fffffff;
        for (int j = 0; j < 64; ++j) {
          if (!((alive >> j) & 1ull)) continue;
          int m = j*64 + lane;
          float mx = X[m], my = X[4096+m], mz = X[8192+m];
          float xxm = __fadd_rn(__fadd_rn(__fmul_rn(mx,mx), __fmul_rn(my,my)), __fmul_rn(mz,mz));
          float dot = __fadd_rn(__fadd_rn(__fmul_rn(qx,mx), __fmul_rn(qy,my)), __fmul_rn(qz,mz));
          float inner = __fmul_rn(-2.0f, dot);
          float dv = __fsub_rn(__fsub_rn(-xxm, inner), xxq);
          bool c0_ = dv > v0, c1_ = dv > v1, c2_ = dv > v2, c3_ = dv > v3;
          float nv1 = c0_ ? v0 : (c1_ ? dv : v1); int ni1 = c0_ ? i0 : (c1_ ? m : i1);
          float nv2 = c1_ ? v1 : (c2_ ? dv : v2); int ni2 = c1_ ? i1 : (c2_ ? m : i2);
          float nv3 = c2_ ? v2 : (c3_ ? dv : v3); int ni3 = c2_ ? i2 : (c3_ ? m : i3);
          v0 = c0_ ? dv : v0; i0 = c0_ ? m : i0;
          v1 = nv1; i1 = ni1; v2 = nv2; i2 = ni2; v3 = nv3; i3 = ni3;
        }
        cnt = 4;
      }
    }
  }
}

// ---------------- MFMA helpers ----------------
__device__ __forceinline__ void zero_acc(f32x4 a[2][4]) {
  #pragma unroll
  for (int mt = 0; mt < 2; ++mt)
    #pragma unroll
    for (int nt = 0; nt < 4; ++nt)
      a[mt][nt] = (f32x4){0.f, 0.f, 0.f, 0.f};
}

__device__ __forceinline__ void load_af(const u16* __restrict__ WB, int m0, int row, int g,
                                        short8 a[2][4]) {
  #pragma unroll
  for (int mt = 0; mt < 2; ++mt)
    #pragma unroll
    for (int kc = 0; kc < 4; ++kc)
      a[mt][kc] = *(const short8*)&WB[(size_t)(m0 + mt*16 + row)*128 + kc*32 + g*8];
}

__device__ __forceinline__ void gemm64(const short8 a[2][4], const uint4* __restrict__ Xs4,
                                       int row, int g, f32x4 acc[2][4]) {
  #pragma unroll
  for (int kc = 0; kc < 4; ++kc) {
    #pragma unroll
    for (int nt = 0; nt < 4; ++nt) {
      int p = nt*16 + row;
      short8 bfr = *(const short8*)&Xs4[p*16 + ((kc*4 + g) ^ (p & 7))];
      acc[0][nt] = __builtin_amdgcn_mfma_f32_16x16x32_bf16(a[0][kc], bfr, acc[0][nt], 0, 0, 0);
      acc[1][nt] = __builtin_amdgcn_mfma_f32_16x16x32_bf16(a[1][kc], bfr, acc[1][nt], 0, 0, 0);
    }
  }
}

// ---------------- per-point GEMMs: phi, psi, alpha on the 8192 original points ----------------
__global__ __launch_bounds__(256) void point_gemms(const u16* __restrict__ featB,
                                                   const u16* __restrict__ WphiB,
                                                   const u16* __restrict__ WpsiB,
                                                   const u16* __restrict__ WalphaB,
                                                   const float* __restrict__ bphi,
                                                   const float* __restrict__ bpsi,
                                                   const float* __restrict__ balpha,
                                                   float* __restrict__ linxi,
                                                   float* __restrict__ psiP,
                                                   float* __restrict__ alphaP)
{
  __shared__ uint4 Xs4[64*16];
  int tid = threadIdx.x, lane = tid & 63, wid = tid >> 6;
  int row = lane & 15, g = lane >> 4, m0 = wid * 32;
  size_t g0 = (size_t)blockIdx.x * 64;
  for (int u = tid; u < 1024; u += 256) {
    int p = u >> 4, seg = u & 15;
    Xs4[p*16 + (seg ^ (p & 7))] = *(const uint4*)&featB[(g0 + p)*128 + seg*8];
  }
  __syncthreads();
  const u16* Ws[3]    = {WphiB, WpsiB, WalphaB};
  const float* bs[3]  = {bphi, bpsi, balpha};
  float* outs[3]      = {linxi, psiP, alphaP};
  #pragma unroll
  for (int w = 0; w < 3; ++w) {
    short8 afr[2][4];
    load_af(Ws[w], m0, row, g, afr);
    f32x4 acc[2][4];
    zero_acc(acc);
    gemm64(afr, Xs4, row, g, acc);
    #pragma unroll
    for (int mt = 0; mt < 2; ++mt) {
      int c = m0 + mt*16 + g*4;
      float4 bp = *(const float4*)&bs[w][c];
      const float* bpp = (const float*)&bp;
      #pragma unroll
      for (int nt = 0; nt < 4; ++nt) {
        int p = nt*16 + row;
        float4 v = make_float4(acc[mt][nt][0]+bpp[0], acc[mt][nt][1]+bpp[1],
                               acc[mt][nt][2]+bpp[2], acc[mt][nt][3]+bpp[3]);
        *(float4*)&outs[w][(g0 + p)*128 + c] = v;
      }
    }
  }
}

// ---------------- pos second moments: per-block partials (deterministic) ----------------
__global__ __launch_bounds__(256) void pos_stats(const float* __restrict__ xyz,
                                                 const int* __restrict__ idx,
                                                 double* __restrict__ part)
{
  __shared__ double rd[256];
  int qg = blockIdx.x*256 + threadIdx.x;
  int b = qg >> 12, n = qg & 4095;
  const float* X = xyz + (size_t)b * 12288;
  float qx = X[n], qy = X[4096+n], qz = X[8192+n];
  double l[9] = {0,0,0,0,0,0,0,0,0};
  for (int kk = 0; kk < 16; ++kk) {
    int nb = idx[(size_t)qg*16 + kk];
    float px = qx - X[nb], py = qy - X[4096+nb], pz = qz - X[8192+nb];
    l[0] += px; l[1] += py; l[2] += pz;
    l[3] += (double)px*px; l[4] += (double)px*py; l[5] += (double)px*pz;
    l[6] += (double)py*py; l[7] += (double)py*pz; l[8] += (double)pz*pz;
  }
  for (int j = 0; j < 9; ++j) {
    __syncthreads();
    rd[threadIdx.x] = l[j];
    __syncthreads();
    for (int s = 128; s > 0; s >>= 1) {
      if (threadIdx.x < s) rd[threadIdx.x] += rd[threadIdx.x + s];
      __syncthreads();
    }
    if (threadIdx.x == 0) part[(size_t)blockIdx.x*9 + j] = rd[0];
  }
}

// ---------------- fold theta BN analytically ----------------
__global__ __launch_bounds__(128) void theta_fold(const double* __restrict__ part,
                                                  const float* __restrict__ Wc,
                                                  const float* __restrict__ bc,
                                                  const float* __restrict__ g,
                                                  const float* __restrict__ be,
                                                  float* __restrict__ WdT,
                                                  float* __restrict__ bd)
{
  int c = threadIdx.x;
  double st[9];
  for (int j = 0; j < 9; ++j) {
    double s = 0.0;
    for (int bk = 0; bk < 32; ++bk) s += part[(size_t)bk*9 + j];
    st[j] = s;
  }
  const double cnt = (double)NNPTS;
  double m0 = st[0]/cnt, m1 = st[1]/cnt, m2 = st[2]/cnt;
  double Pxx = st[3]/cnt, Pxy = st[4]/cnt, Pxz = st[5]/cnt;
  double Pyy = st[6]/cnt, Pyz = st[7]/cnt, Pzz = st[8]/cnt;
  double w0 = Wc[c*3], w1 = Wc[c*3+1], w2 = Wc[c*3+2], bb = bc[c];
  double wm = w0*m0 + w1*m1 + w2*m2;
  double mu = wm + bb;
  double quad = w0*(Pxx*w0 + Pxy*w1 + Pxz*w2)
              + w1*(Pxy*w0 + Pyy*w1 + Pyz*w2)
              + w2*(Pxz*w0 + Pyz*w1 + Pzz*w2);
  double Ex2 = quad + 2.0*bb*wm + bb*bb;
  double var = Ex2 - mu*mu;
  double s = (double)g[c] / sqrt(var + 1e-5);
  double t = (double)be[c] - s*mu;
  WdT[0*128+c] = (float)(s*w0);
  WdT[1*128+c] = (float)(s*w1);
  WdT[2*128+c] = (float)(s*w2);
  bd[c] = (float)(s*bb + t);
}

// ---------------- gamma BN stats: stage 1 ----------------
__global__ __launch_bounds__(256) void gamma_part(const float* __restrict__ gs,
                                                  const float* __restrict__ gq,
                                                  double* __restrict__ partS,
                                                  double* __restrict__ partQ)
{
  int c = threadIdx.x & 127;
  int arr = threadIdx.x >> 7;
  int j = blockIdx.x;
  const float* src = arr ? gq : gs;
  double s = 0.0;
  #pragma unroll 8
  for (int bk = j*32; bk < j*32 + 32; ++bk)
    s += src[(size_t)bk*128 + c];
  (arr ? partQ : partS)[(size_t)j*128 + c] = s;
}

// ---------------- gamma BN stats: stage 2 ----------------
__global__ __launch_bounds__(128) void gamma_final(const double* __restrict__ partS,
                                                   const double* __restrict__ partQ,
                                                   const float* __restrict__ g,
                                                   const float* __restrict__ be,
                                                   float* __restrict__ s2,
                                                   float* __restrict__ t2v)
{
  int c = threadIdx.x;
  double S = 0.0, Q = 0.0;
  #pragma unroll 8
  for (int j = 0; j < 64; ++j) {
    S += partS[(size_t)j*128 + c];
    Q += partQ[(size_t)j*128 + c];
  }
  const double cnt = (double)NNPTS;
  double m = S/cnt, v = Q/cnt - m*m;
  double s = (double)g[c] / sqrt(v + 1e-5);
  s2[c]  = (float)s;
  t2v[c] = (float)((double)be[c] - s*m);
}

// ---------------- fused pass: assemble rel0 (gathered psi + delta) -> fus GEMM -> g2 bf16 + stats ----------------
__global__ __launch_bounds__(256) void fused_pass(
    const float* __restrict__ psiP, const float* __restrict__ linxi,
    const int* __restrict__ idx, const float* __restrict__ xyz,
    const u16* __restrict__ WfusB, const float* __restrict__ c0,
    const float* __restrict__ WdT, const float* __restrict__ bd,
    u16* __restrict__ g2W,
    float* __restrict__ gs, float* __restrict__ gq)
{
  __shared__ uint4 XsR[64*16];                 // rel0 bf16, swizzled
  __shared__ float LxS[4][128];
  __shared__ float WdS[4][128];                // wd0,wd1,wd2,bd
  __shared__ float posS[3][64];
  __shared__ int   pidx[64];
  __shared__ float redS[128], redQ[128];

  int tid = threadIdx.x, lane = tid & 63, wid = tid >> 6;
  int row = lane & 15, g = lane >> 4;
  int m0 = wid * 32;
  int q0 = blockIdx.x * 4, b = q0 >> 12;
  int n0 = q0 & 4095;
  const float* X = xyz + (size_t)b * 12288;
  size_t gp0 = (size_t)blockIdx.x * 64;
  size_t b12 = (size_t)b << 12;

  if (tid < 64) {
    int q = tid >> 4;
    int nb = idx[(size_t)(q0 + q)*16 + (tid & 15)];
    pidx[tid] = nb;
    int nq = n0 + q;
    posS[0][tid] = X[nq]      - X[nb];
    posS[1][tid] = X[4096+nq] - X[4096+nb];
    posS[2][tid] = X[8192+nq] - X[8192+nb];
  }
  for (int u = tid; u < 512; u += 256) {
    LxS[u >> 7][u & 127] = linxi[(size_t)q0*128 + u];
    WdS[u >> 7][u & 127] = (u < 384) ? WdT[u] : bd[u & 127];
  }
  __syncthreads();

  // assemble rel0 = linxi - psiP[b12 + pidx] + delta  (bf16 swizzled into XsR)
  #pragma unroll
  for (int it = 0; it < 4; ++it) {
    int u = tid + it*256;
    int p = u >> 4, seg = u & 15;
    int q = p >> 4, cc = seg * 8;
    float p0 = posS[0][p], p1 = posS[1][p], p2 = posS[2][p];
    const float* psir = &psiP[(b12 + (size_t)pidx[p])*128 + cc];
    float ps[8];
    *(float4*)&ps[0] = *(const float4*)&psir[0];
    *(float4*)&ps[4] = *(const float4*)&psir[4];
    ushort4 lohi[2];
    u16* wv = (u16*)lohi;
    #pragma unroll
    for (int r = 0; r < 8; ++r) {
      int c = cc + r;
      float d = fmaf(WdS[2][c], p2, fmaf(WdS[1][c], p1, fmaf(WdS[0][c], p0, WdS[3][c])));
      d = fmaxf(d, 0.f);
      wv[r] = f2bf(LxS[q][c] - ps[r] + d);
    }
    XsR[p*16 + (seg ^ (p & 7))] = *(uint4*)lohi;
  }
  __syncthreads();

  // ---- fused gamma GEMM on rel0 ----
  short8 afr[2][4];
  f32x4 acc[2][4];
  load_af(WfusB, m0, row, g, afr);
  zero_acc(acc);
  gemm64(afr, XsR, row, g, acc);

  // ---- gg = fus + c0 -> global bf16, + per-block stats partials ----
  #pragma unroll
  for (int mt = 0; mt < 2; ++mt) {
    int c = m0 + mt*16 + g*4;
    float4 c0v = *(const float4*)&c0[c];
    const float* c0p = (const float*)&c0v;
    float sv[4], qv[4];
    #pragma unroll
    for (int r = 0; r < 4; ++r) { sv[r] = 0.f; qv[r] = 0.f; }
    #pragma unroll
    for (int nt = 0; nt < 4; ++nt) {
      int p = nt*16 + row;
      ushort4 v;
      u16* vv = (u16*)&v;
      #pragma unroll
      for (int r = 0; r < 4; ++r) {
        float gg = acc[mt][nt][r] + c0p[r];
        vv[r] = f2bf(gg);
        sv[r] += gg; qv[r] = fmaf(gg, gg, qv[r]);
      }
      *(ushort4*)&g2W[(gp0 + p)*128 + c] = v;
    }
    #pragma unroll
    for (int r = 0; r < 4; ++r) {
      #pragma unroll
      for (int d = 1; d < 16; d <<= 1) {
        sv[r] += __shfl_xor(sv[r], d);
        qv[r] += __shfl_xor(qv[r], d);
      }
    }
    if (row == 0) {
      *(float4*)&redS[c] = make_float4(sv[0], sv[1], sv[2], sv[3]);
      *(float4*)&redQ[c] = make_float4(qv[0], qv[1], qv[2], qv[3]);
    }
  }
  __syncthreads();
  if (tid < 128) {
    gs[(size_t)blockIdx.x*128 + tid] = redS[tid];
    gq[(size_t)blockIdx.x*128 + tid] = redQ[tid];
  }
}

// ---------------- streaming epilogue: BN+relu -> softmax over K -> weighted sum ----------------
__global__ __launch_bounds__(256) void out_kernel(const u16* __restrict__ g2W,
                                                  const float* __restrict__ alphaP,
                                                  const int* __restrict__ idx,
                                                  const float* __restrict__ xyz,
                                                  const float* __restrict__ WdT,
                                                  const float* __restrict__ bd,
                                                  const float* __restrict__ s2,
                                                  const float* __restrict__ t2v,
                                                  float* __restrict__ out)
{
  __shared__ int   pidxO[8][16];
  __shared__ float posO[3][8][16];
  int tid = threadIdx.x;
  int c = tid & 127;
  int qg = tid >> 7;                 // 0..1
  int q0 = blockIdx.x * 8;           // 8 queries per block
  int bb = q0 >> 12;
  size_t bOff = (size_t)bb << 12;
  const float* X = xyz + (size_t)bb * 12288;
  if (tid < 128) {
    int q = tid >> 4, k = tid & 15;
    int gq = q0 + q;
    int nq = gq & 4095;
    int nb = idx[(size_t)gq*16 + k];
    pidxO[q][k] = nb;
    posO[0][q][k] = X[nq]      - X[nb];
    posO[1][q][k] = X[4096+nq] - X[4096+nb];
    posO[2][q][k] = X[8192+nq] - X[8192+nb];
  }
  float s = s2[c], t = t2v[c];
  float w0 = WdT[c], w1 = WdT[128+c], w2 = WdT[256+c], bdv = bd[c];
  __syncthreads();
  #pragma unroll
  for (int qi = 0; qi < 4; ++qi) {
    int ql = qi*2 + qg;
    int gq = q0 + ql;
    int b = gq >> 12, n = gq & 4095;
    size_t base = (size_t)gq*2048 + c;   // gq*16*128
    float rel[16], Fv[16];
    #pragma unroll
    for (int k = 0; k < 16; ++k) {
      float gg = bf2f(g2W[base + (size_t)k*128]);
      rel[k] = fmaxf(fmaf(s, gg, t), 0.f);
      float d = fmaf(w2, posO[2][ql][k], fmaf(w1, posO[1][ql][k], fmaf(w0, posO[0][ql][k], bdv)));
      d = fmaxf(d, 0.f);
      Fv[k] = alphaP[(bOff + (size_t)pidxO[ql][k])*128 + c] + d;
    }
    float m = rel[0];
    #pragma unroll
    for (int k = 1; k < 16; ++k) m = fmaxf(m, rel[k]);
    float se = 0.f, so = 0.f;
    #pragma unroll
    for (int k = 0; k < 16; ++k) {
      float e = expf(rel[k] - m);
      se += e; so = fmaf(e, Fv[k], so);
    }
    out[(((size_t)b*128 + c) << 12) + n] = so / se;
  }
}

extern "C" void kernel_launch(void* const* d_in, const int* in_sizes, int n_in,
                              void* d_out, int out_size, void* d_ws, size_t ws_size,
                              hipStream_t stream)
{
  const float* xyz      = (const float*)d_in[0];
  const float* features = (const float*)d_in[1];
  const float* wt1      = (const float*)d_in[2];
  const float* bt1      = (const float*)d_in[3];
  const float* wt2      = (const float*)d_in[4];
  const float* bt2      = (const float*)d_in[5];
  const float* gth      = (const float*)d_in[6];
  const float* bth      = (const float*)d_in[7];
  const float* wphi     = (const float*)d_in[8];
  const float* bphi     = (const float*)d_in[9];
  const float* wpsi     = (const float*)d_in[10];
  const float* bpsi     = (const float*)d_in[11];
  const float* walpha   = (const float*)d_in[12];
  const float* balpha   = (const float*)d_in[13];
  const float* wg1      = (const float*)d_in[14];
  const float* bg1      = (const float*)d_in[15];
  const float* wg2      = (const float*)d_in[16];
  const float* bg2      = (const float*)d_in[17];
  const float* gga      = (const float*)d_in[18];
  const float* bga      = (const float*)d_in[19];

  char* w = (char*)d_ws;
  size_t off = 0;
  auto take = [&](size_t bytes) -> void* {
    void* p = w + off;
    off = (off + bytes + 255) & ~(size_t)255;
    return p;
  };
  int*    idxW    = (int*)   take((size_t)NQ*16*4);
  u16*    featB   = (u16*)   take((size_t)NQ*128*2);
  float*  linxi   = (float*) take((size_t)NQ*128*4);
  float*  psiP    = (float*) take((size_t)NQ*128*4);
  float*  alphaP  = (float*) take((size_t)NQ*128*4);
  u16*    WphiB   = (u16*)   take(32768);
  u16*    WpsiB   = (u16*)   take(32768);
  u16*    WalphaB = (u16*)   take(32768);
  u16*    WfusB   = (u16*)   take(32768);
  float*  c0      = (float*) take(512);
  float*  Wc      = (float*) take(1536);
  float*  bc      = (float*) take(512);
  float*  WdT     = (float*) take(1536);
  float*  bd      = (float*) take(512);
  double* part    = (double*)take(32*9*8);
  float*  gs      = (float*) take((size_t)2048*128*4);
  float*  gq      = (float*) take((size_t)2048*128*4);
  double* partS   = (double*)take((size_t)64*128*8);
  double* partQ   = (double*)take((size_t)64*128*8);
  float*  s2      = (float*) take(512);
  float*  t2v     = (float*) take(512);
  u16*    g2W     = (u16*)   take((size_t)NNPTS*128*2);
  float*  out     = (float*)d_out;

  transpose_feat<<<dim3(64, 2, 2), 256, 0, stream>>>(features, featB);
  prep_weights<<<128, 128, 0, stream>>>(wphi, wpsi, walpha, wg1, wg2, bg1, bg2,
                                        wt1, bt1, wt2, bt2,
                                        WphiB, WpsiB, WalphaB, WfusB, c0, Wc, bc);
  knn_kernel<<<2048, 256, 0, stream>>>(xyz, idxW);
  point_gemms<<<128, 256, 0, stream>>>(featB, WphiB, WpsiB, WalphaB,
                                       bphi, bpsi, balpha, linxi, psiP, alphaP);
  pos_stats<<<32, 256, 0, stream>>>(xyz, idxW, part);
  theta_fold<<<1, 128, 0, stream>>>(part, Wc, bc, gth, bth, WdT, bd);
  fused_pass<<<2048, 256, 0, stream>>>(psiP, linxi, idxW, xyz,
      WfusB, c0, WdT, bd, g2W, gs, gq);
  gamma_part<<<64, 256, 0, stream>>>(gs, gq, partS, partQ);
  gamma_final<<<1, 128, 0, stream>>>(partS, partQ, gga, bga, s2, t2v);
  out_kernel<<<1024, 256, 0, stream>>>(g2W, alphaP, idxW, xyz, WdT, bd, s2, t2v, out);
}